// Round 12
// baseline (358.018 us; speedup 1.0000x reference)
//
#include <hip/hip_runtime.h>
#include <hip/hip_fp16.h>
#include <cstdint>
#include <cstddef>

#define SLOPE 0.2f
#define EPSV 1e-10f

#define BSHIFT 7                  // 128 nodes per sort bucket
#define BNODES (1 << BSHIFT)
#define NBMAX 1024                // bucket array bound for N <= 131072
#define BCAP 3584                 // fixed records/bucket region (mean 2048 + 34 sigma)
#define SEG_CAP 2816              // records per bucket LDS segment (mean + 17 sigma)
#define BIN_TPB 1024
#define BIN_EPT 4                 // 4096 edges/block (R7/R11's proven burst size), 16 waves/block
#define BM 64

#define DOT4(F, Q) ((F).x*(Q).x + (F).y*(Q).y + (F).z*(Q).z + (F).w*(Q).w)

__device__ __forceinline__ float h2_as_float(__half2 v) {
  union { __half2 h; float f; } u; u.h = v; return u.f;
}
__device__ __forceinline__ __half2 float_as_h2(float v) {
  union { float f; __half2 h; } u; u.f = v; return u.h;
}
__device__ __forceinline__ __half2 u_as_h2(unsigned v) {
  union { unsigned u; __half2 h; } un; un.u = v; return un.h;
}
__device__ __forceinline__ unsigned h2_as_u(__half2 v) {
  union { __half2 h; unsigned u; } un; un.h = v; return un.u;
}

typedef float fv4 __attribute__((ext_vector_type(4)));
typedef int   iv2 __attribute__((ext_vector_type(2)));

__device__ __forceinline__ float4 ntload4(const float4* p) {
  fv4 v = __builtin_nontemporal_load((const fv4*)p);
  float4 r; r.x = v.x; r.y = v.y; r.z = v.z; r.w = v.w; return r;
}
__device__ __forceinline__ int2 ntload2i(const int2* p) {
  iv2 v = __builtin_nontemporal_load((const iv2*)p);
  int2 r; r.x = v.x; r.y = v.y; return r;
}
__device__ __forceinline__ float ntloadf(const float* p) {
  return __builtin_nontemporal_load(p);
}
__device__ __forceinline__ void ntstore4(float* p, float4 v) {
  fv4 t; t.x = v.x; t.y = v.y; t.z = v.z; t.w = v.w;
  __builtin_nontemporal_store(t, (fv4*)p);
}

// K0: Qe[h][k], cb[h] precompute + bcur preset (bcur[b] = b*BCAP — the fixed
// per-bucket region bases that replace the global count+scan stage).
__global__ void prep_qe(const float* __restrict__ We, const float* __restrict__ be,
                        const float* __restrict__ query, float* __restrict__ Qe,
                        float* __restrict__ cb, unsigned* __restrict__ bcur,
                        int nbkt) {
  int tid = threadIdx.x;  // 64 threads
  for (int i = tid; i < nbkt; i += 64) bcur[i] = (unsigned)i * BCAP;
  int h = tid >> 4, k = tid & 15;
  float acc = 0.f;
  for (int t = 0; t < 16; ++t) {
    float qs = query[h*32 + 2*t] + query[h*32 + 2*t + 1];
    acc += qs * We[(16*h + t)*16 + k];
  }
  Qe[h*16 + k] = acc;
  if (k == 0) {
    float accb = 0.f;
    for (int t = 0; t < 16; ++t) {
      float qs = query[h*32 + 2*t] + query[h*32 + 2*t + 1];
      accb += qs * be[16*h + t];
    }
    cb[h] = accb;
  }
}

// K1: hidden = x @ W^T + b (stored FP16), fused A[n,h], B[n,h] projections.
// Register-tiled SGEMM: 64 rows/block, 256 threads, 4x4 acc tile per thread,
// XOR-swizzled LDS operands (b128 reads at 2-way = free). [proven R6-R11]
__global__ __launch_bounds__(256) void hidden_ab(
    const float* __restrict__ x, const float* __restrict__ W,
    const float* __restrict__ b, const float* __restrict__ query,
    __half* __restrict__ hidden_h, float* __restrict__ Av, float* __restrict__ Bv,
    int N) {
  __shared__ float wt[128 * 64];   // wt[k*64 + (c ^ ((k&7)<<2))]
  __shared__ float xs[BM * 128];   // xs[r*128 + (k ^ ((r&7)<<2))]
  int t = threadIdx.x;
  int rowbase = blockIdx.x * BM;

#pragma unroll
  for (int i = 0; i < 32; ++i) {
    int idx = t + 256 * i;            // 0..8191 over flat W[c*128+k]
    int c = idx >> 7, k = idx & 127;
    wt[k * 64 + (c ^ ((k & 7) << 2))] = W[idx];
  }
#pragma unroll
  for (int i = 0; i < 8; ++i) {
    int idx4 = t + 256 * i;           // 0..2047 float4s (64 rows x 32)
    int r = idx4 >> 5, kc4 = idx4 & 31;
    int row = rowbase + r;
    float4 v = (row < N) ? ((const float4*)x)[(size_t)row * 32 + kc4]
                         : make_float4(0.f, 0.f, 0.f, 0.f);
    *(float4*)&xs[r * 128 + ((kc4 * 4) ^ ((r & 7) << 2))] = v;
  }
  __syncthreads();

  int tc = t & 15;            // col group: cols tc*4..tc*4+3
  int trg = t >> 4;           // row group: local rows trg*4..trg*4+3
  int c0 = tc * 4;
  const float* xb0 = &xs[(trg * 4 + 0) * 128];
  const float* xb1 = &xs[(trg * 4 + 1) * 128];
  const float* xb2 = &xs[(trg * 4 + 2) * 128];
  const float* xb3 = &xs[(trg * 4 + 3) * 128];
  const int sx0 = ((trg * 4 + 0) & 7) << 2;
  const int sx1 = ((trg * 4 + 1) & 7) << 2;
  const int sx2 = ((trg * 4 + 2) & 7) << 2;
  const int sx3 = ((trg * 4 + 3) & 7) << 2;

  float acc[4][4];
#pragma unroll
  for (int i = 0; i < 4; ++i)
#pragma unroll
    for (int j = 0; j < 4; ++j) acc[i][j] = 0.f;

#define ACCROW(i, XA) \
  acc[i][0] += (XA).x*wb0.x + (XA).y*wb1.x + (XA).z*wb2.x + (XA).w*wb3.x; \
  acc[i][1] += (XA).x*wb0.y + (XA).y*wb1.y + (XA).z*wb2.y + (XA).w*wb3.y; \
  acc[i][2] += (XA).x*wb0.z + (XA).y*wb1.z + (XA).z*wb2.z + (XA).w*wb3.z; \
  acc[i][3] += (XA).x*wb0.w + (XA).y*wb1.w + (XA).z*wb2.w + (XA).w*wb3.w;

#pragma unroll 2
  for (int k = 0; k < 128; k += 4) {
    float4 xa0 = *(const float4*)(xb0 + (k ^ sx0));
    float4 xa1 = *(const float4*)(xb1 + (k ^ sx1));
    float4 xa2 = *(const float4*)(xb2 + (k ^ sx2));
    float4 xa3 = *(const float4*)(xb3 + (k ^ sx3));
    float4 wb0 = *(const float4*)&wt[(k + 0) * 64 + (c0 ^ (((k + 0) & 7) << 2))];
    float4 wb1 = *(const float4*)&wt[(k + 1) * 64 + (c0 ^ (((k + 1) & 7) << 2))];
    float4 wb2 = *(const float4*)&wt[(k + 2) * 64 + (c0 ^ (((k + 2) & 7) << 2))];
    float4 wb3 = *(const float4*)&wt[(k + 3) * 64 + (c0 ^ (((k + 3) & 7) << 2))];
    ACCROW(0, xa0)
    ACCROW(1, xa1)
    ACCROW(2, xa2)
    ACCROW(3, xa3)
  }
#undef ACCROW

  float4 bv4 = ((const float4*)b)[tc];
  int h = tc >> 2;
  float qa[4], qb[4];
#pragma unroll
  for (int j = 0; j < 4; ++j) {
    int tt = (tc & 3) * 4 + j;
    qa[j] = query[h * 32 + 2 * tt];
    qb[j] = query[h * 32 + 2 * tt + 1];
  }
  float pa[4], pb[4];
#pragma unroll
  for (int i = 0; i < 4; ++i) {
    int row = rowbase + trg * 4 + i;
    float4 v;
    v.x = acc[i][0] + bv4.x; v.y = acc[i][1] + bv4.y;
    v.z = acc[i][2] + bv4.z; v.w = acc[i][3] + bv4.w;
    if (row < N) {
      uint2 hv;
      hv.x = h2_as_u(__floats2half2_rn(v.x, v.y));
      hv.y = h2_as_u(__floats2half2_rn(v.z, v.w));
      *(uint2*)(hidden_h + (size_t)row * 64 + c0) = hv;
    }
    pa[i] = qa[0]*v.x + qa[1]*v.y + qa[2]*v.z + qa[3]*v.w;
    pb[i] = qb[0]*v.x + qb[1]*v.y + qb[2]*v.z + qb[3]*v.w;
  }
#pragma unroll
  for (int mask = 1; mask <= 2; mask <<= 1) {
#pragma unroll
    for (int i = 0; i < 4; ++i) {
      pa[i] += __shfl_xor(pa[i], mask);
      pb[i] += __shfl_xor(pb[i], mask);
    }
  }
  if ((tc & 3) == 0) {
#pragma unroll
    for (int i = 0; i < 4; ++i) {
      int row = rowbase + trg * 4 + i;
      if (row < N) {
        Av[(size_t)row * 4 + h] = pa[i];
        Bv[(size_t)row * 4 + h] = pb[i];
      }
    }
  }
}

// K3: fused compute + bucket-bin. R11 post-mortem: still latency-bound
// (VALUBusy 7%, Occ 21%) with the cap being the GRID: 391 blocks / 256 CUs
// = 1.5 blocks/CU = 12 waves/CU. R9 proved more-blocks shrinks bursts
// (WRITE amp up, net loss). Third axis: TPB 512->1024 with EPT 8->4 keeps
// edges/block at 4096 (per-(block,bucket) burst ~5.2 records UNCHANGED ->
// WRITE amp unchanged) while doubling waves/block: ~24 waves/CU average.
// Body otherwise identical to the R7/R11 measured-best shape.
__global__ __launch_bounds__(BIN_TPB) void edge_aa_bin(
    const int* __restrict__ el, const float* __restrict__ ew_arr,
    const float* __restrict__ ef,
    const float* __restrict__ Av, const float* __restrict__ Bv,
    const float* __restrict__ Qe, const float* __restrict__ cb,
    unsigned* __restrict__ bcur, float4* __restrict__ recB, int E, int nbkt) {
  __shared__ unsigned hist[NBMAX];
  __shared__ unsigned lbase[NBMAX];
  int t = threadIdx.x;
  int m0 = blockIdx.x * (BIN_TPB * BIN_EPT);
  for (int i = t; i < nbkt; i += BIN_TPB) hist[i] = 0u;
  __syncthreads();
  float4 r[BIN_EPT];
  int bkt[BIN_EPT];
  const float4* q4 = (const float4*)Qe;
#pragma unroll
  for (int k = 0; k < BIN_EPT; ++k) {
    int m = m0 + t + BIN_TPB * k;
    bkt[k] = -1;
    if (m < E) {
      int2 e2 = ntload2i((const int2*)el + m);
      const float4* ef4 = (const float4*)(ef + (size_t)m * 16);
      float4 f0 = ntload4(ef4 + 0), f1 = ntload4(ef4 + 1);
      float4 f2 = ntload4(ef4 + 2), f3 = ntload4(ef4 + 3);
      float w0, w1, w2, w3;
      {
        float4 q;
        q = q4[0];  w0  = DOT4(f0, q);  q = q4[1];  w0 += DOT4(f1, q);
        q = q4[2];  w0 += DOT4(f2, q);  q = q4[3];  w0 += DOT4(f3, q);
        q = q4[4];  w1  = DOT4(f0, q);  q = q4[5];  w1 += DOT4(f1, q);
        q = q4[6];  w1 += DOT4(f2, q);  q = q4[7];  w1 += DOT4(f3, q);
        q = q4[8];  w2  = DOT4(f0, q);  q = q4[9];  w2 += DOT4(f1, q);
        q = q4[10]; w2 += DOT4(f2, q);  q = q4[11]; w2 += DOT4(f3, q);
        q = q4[12]; w3  = DOT4(f0, q);  q = q4[13]; w3 += DOT4(f1, q);
        q = q4[14]; w3 += DOT4(f2, q);  q = q4[15]; w3 += DOT4(f3, q);
      }
      float4 av = ((const float4*)Av)[e2.x];
      float4 bv = ((const float4*)Bv)[e2.y];
      w0 += av.x + bv.x + cb[0];
      w1 += av.y + bv.y + cb[1];
      w2 += av.z + bv.z + cb[2];
      w3 += av.w + bv.w + cb[3];
      w0 = w0 > 0.f ? w0 : SLOPE * w0;
      w1 = w1 > 0.f ? w1 : SLOPE * w1;
      w2 = w2 > 0.f ? w2 : SLOPE * w2;
      w3 = w3 > 0.f ? w3 : SLOPE * w3;
      float ew = ntloadf(ew_arr + m);
      float a0 = __expf(w0) * ew, a1 = __expf(w1) * ew;
      float a2 = __expf(w2) * ew, a3 = __expf(w3) * ew;
      r[k].x = __int_as_float(e2.x);
      r[k].y = h2_as_float(__floats2half2_rn(a0, a1));
      r[k].z = h2_as_float(__floats2half2_rn(a2, a3));
      r[k].w = __int_as_float(e2.y);
      bkt[k] = e2.y >> BSHIFT;
      atomicAdd(&hist[bkt[k]], 1u);
    }
  }
  __syncthreads();
  for (int i = t; i < nbkt; i += BIN_TPB) {
    unsigned c = hist[i];
    lbase[i] = c ? atomicAdd(&bcur[i], c) : 0u;
  }
  __syncthreads();
  for (int i = t; i < nbkt; i += BIN_TPB) hist[i] = 0u;
  __syncthreads();
#pragma unroll
  for (int k = 0; k < BIN_EPT; ++k) {
    if (bkt[k] >= 0) {
      unsigned p = lbase[bkt[k]] + atomicAdd(&hist[bkt[k]], 1u);
      if (p < (unsigned)(bkt[k] + 1) * BCAP)   // overflow guard (34-sigma)
        recB[p] = r[k];
    }
  }
}

// K4: fused CSR-build + gather. One block per 128-node bucket: in-block
// histogram of nout&127 over the bucket span, 128-wide Hillis-Steele scan,
// L2-hot re-read scattering into the 12B/record LDS segment, then the proven
// 4-group x 16-lane gather with 2-way unrolled hidden loads (2x MLP).
// Block-uniform fallback (len > SEG_CAP, ~never): full-span scan per node.
__global__ __launch_bounds__(512) void gather_sorted(
    const unsigned* __restrict__ bcur, const float4* __restrict__ recB,
    const float* __restrict__ Av, const float* __restrict__ Bv,
    const __half* __restrict__ hidden_h, float* __restrict__ out, int N) {
  __shared__ unsigned seg_nin[SEG_CAP];
  __shared__ uint2    seg_aa[SEG_CAP];
  __shared__ unsigned cnt[BNODES];      // counts -> inclusive scan
  __shared__ unsigned rp2[BNODES + 1];  // exclusive offsets
  __shared__ unsigned cur[BNODES];
  int t = threadIdx.x;
  int b = blockIdx.x;
  int n0 = b << BSHIFT;
  int nCnt = N - n0; if (nCnt > BNODES) nCnt = BNODES;
  unsigned base = (unsigned)b * BCAP;
  unsigned len = bcur[b] - base;
  if (len > BCAP) len = BCAP;
  if (t < BNODES) cnt[t] = 0u;
  __syncthreads();

  // pass 1: per-node histogram over the bucket span
  for (unsigned i = t; i < len; i += 512) {
    float4 r = recB[base + i];
    int nloc = __float_as_int(r.w) & (BNODES - 1);
    atomicAdd(&cnt[nloc], 1u);
  }
  __syncthreads();
  // inclusive Hillis-Steele scan over cnt[0..127] (block-uniform barriers)
  for (int off = 1; off < BNODES; off <<= 1) {
    unsigned v = (t < BNODES && t >= off) ? cnt[t - off] : 0u;
    __syncthreads();
    if (t < BNODES) cnt[t] += v;
    __syncthreads();
  }
  if (t < BNODES) rp2[t + 1] = cnt[t];
  if (t == 0) rp2[0] = 0u;
  __syncthreads();
  if (t < BNODES) cur[t] = rp2[t];
  __syncthreads();

  bool fits = (len <= SEG_CAP);
  if (fits) {
    // pass 2: L2-hot re-read, scatter into LDS segment at exact CSR offsets
    for (unsigned i = t; i < len; i += 512) {
      float4 r = recB[base + i];
      int nloc = __float_as_int(r.w) & (BNODES - 1);
      unsigned p = atomicAdd(&cur[nloc], 1u);
      seg_nin[p] = (unsigned)__float_as_int(r.x);
      seg_aa[p] = make_uint2(__float_as_uint(r.y), __float_as_uint(r.z));
    }
  }
  __syncthreads();

  int w = t >> 6, lane = t & 63;
  int g = lane >> 4, j = lane & 15, h = j >> 2;
  for (int loc = w; loc < nCnt; loc += 8) {
    int n = n0 + loc;
    unsigned i0 = rp2[loc], i1 = rp2[loc + 1];
    float4 acc = make_float4(0.f, 0.f, 0.f, 0.f);
    float nsum = 0.f;

    if (g == 0) {
      float4 av = ((const float4*)Av)[n];
      float4 bv = ((const float4*)Bv)[n];
      float avh = (h == 0) ? av.x : (h == 1) ? av.y : (h == 2) ? av.z : av.w;
      float bvh = (h == 0) ? bv.x : (h == 1) ? bv.y : (h == 2) ? bv.z : bv.w;
      float wsl = avh + bvh;
      wsl = wsl > 0.f ? wsl : SLOPE * wsl;
      float aas = __expf(wsl);
      nsum = aas;
      uint2 hv = *(const uint2*)(hidden_h + (size_t)n * 64 + 4 * j);
      float2 f01 = __half22float2(u_as_h2(hv.x));
      float2 f23 = __half22float2(u_as_h2(hv.y));
      acc.x = aas * f01.x; acc.y = aas * f01.y;
      acc.z = aas * f23.x; acc.w = aas * f23.y;
    }

    if (fits) {
      for (unsigned idx = i0 + g; idx < i1; idx += 8) {
        unsigned nin1 = seg_nin[idx];
        uint2 aa1 = seg_aa[idx];
        uint2 hv1 = *(const uint2*)(hidden_h + (size_t)nin1 * 64 + 4 * j);
        unsigned idx2 = idx + 4;
        bool have2 = (idx2 < i1);
        unsigned nin2 = 0; uint2 aa2 = make_uint2(0u, 0u);
        uint2 hv2 = make_uint2(0u, 0u);
        if (have2) {
          nin2 = seg_nin[idx2];
          aa2 = seg_aa[idx2];
          hv2 = *(const uint2*)(hidden_h + (size_t)nin2 * 64 + 4 * j);
        }
        {
          __half2 aa01 = u_as_h2(aa1.x), aa23 = u_as_h2(aa1.y);
          float aa = (h == 0) ? __low2float(aa01) : (h == 1) ? __high2float(aa01)
                   : (h == 2) ? __low2float(aa23) : __high2float(aa23);
          float2 f01 = __half22float2(u_as_h2(hv1.x));
          float2 f23 = __half22float2(u_as_h2(hv1.y));
          nsum += aa;
          acc.x += aa * f01.x; acc.y += aa * f01.y;
          acc.z += aa * f23.x; acc.w += aa * f23.y;
        }
        if (have2) {
          __half2 aa01 = u_as_h2(aa2.x), aa23 = u_as_h2(aa2.y);
          float aa = (h == 0) ? __low2float(aa01) : (h == 1) ? __high2float(aa01)
                   : (h == 2) ? __low2float(aa23) : __high2float(aa23);
          float2 f01 = __half22float2(u_as_h2(hv2.x));
          float2 f23 = __half22float2(u_as_h2(hv2.y));
          nsum += aa;
          acc.x += aa * f01.x; acc.y += aa * f01.y;
          acc.z += aa * f23.x; acc.w += aa * f23.y;
        }
      }
    } else {
      for (unsigned i = g; i < len; i += 4) {
        float4 rr = recB[base + i];
        int nloc = __float_as_int(rr.w) & (BNODES - 1);
        if (nloc != loc) continue;
        int nin = __float_as_int(rr.x);
        __half2 aa01 = float_as_h2(rr.y);
        __half2 aa23 = float_as_h2(rr.z);
        float aa = (h == 0) ? __low2float(aa01) : (h == 1) ? __high2float(aa01)
                 : (h == 2) ? __low2float(aa23) : __high2float(aa23);
        uint2 hv = *(const uint2*)(hidden_h + (size_t)nin * 64 + 4 * j);
        float2 f01 = __half22float2(u_as_h2(hv.x));
        float2 f23 = __half22float2(u_as_h2(hv.y));
        nsum += aa;
        acc.x += aa * f01.x; acc.y += aa * f01.y;
        acc.z += aa * f23.x; acc.w += aa * f23.y;
      }
    }

#pragma unroll
    for (int mask = 16; mask <= 32; mask <<= 1) {
      acc.x += __shfl_xor(acc.x, mask);
      acc.y += __shfl_xor(acc.y, mask);
      acc.z += __shfl_xor(acc.z, mask);
      acc.w += __shfl_xor(acc.w, mask);
      nsum  += __shfl_xor(nsum, mask);
    }
    if (g == 0) {
      float c = (float)(i1 - i0 + 1u);
      float F = 1.f / ((nsum / c + EPSV) * c);
      float4 v;
      v.x = acc.x * F; v.y = acc.y * F; v.z = acc.z * F; v.w = acc.w * F;
      v.x = v.x > 0.f ? v.x : 0.f;
      v.y = v.y > 0.f ? v.y : 0.f;
      v.z = v.z > 0.f ? v.z : 0.f;
      v.w = v.w > 0.f ? v.w : 0.f;
      ntstore4(out + (size_t)n * 64 + 4 * j, v);
    }
  }
}

extern "C" void kernel_launch(void* const* d_in, const int* in_sizes, int n_in,
                              void* d_out, int out_size, void* d_ws, size_t ws_size,
                              hipStream_t stream) {
  const int*   el = (const int*)d_in[0];
  const float* ew = (const float*)d_in[1];
  const float* ef = (const float*)d_in[2];
  const float* x  = (const float*)d_in[4];
  const float* W  = (const float*)d_in[5];
  const float* b  = (const float*)d_in[6];
  const float* We = (const float*)d_in[7];
  const float* be = (const float*)d_in[8];
  const float* q  = (const float*)d_in[9];
  int E = in_sizes[0] / 2;
  int N = in_sizes[4] / 128;
  int NB = (N + BNODES - 1) >> BSHIFT;     // 782 for N=100k

  float* ws = (float*)d_ws;
  size_t off = 0;
  __half* hidden_h = (__half*)(ws + off); off += (size_t)N * 32;   // N*64 halves
  float4* recB  = (float4*)(ws + off); off += (size_t)NB * BCAP * 4 + 16;
  float* Av     = ws + off; off += (size_t)N * 4;
  float* Bv     = ws + off; off += (size_t)N * 4;
  unsigned* bcur = (unsigned*)(ws + off); off += NBMAX;
  float* Qe     = ws + off; off += 64;
  float* cb     = ws + off; off += 4;
  float* outp   = (float*)d_out;

  int bb = (E + BIN_TPB * BIN_EPT - 1) / (BIN_TPB * BIN_EPT);     // 391

  prep_qe<<<1, 64, 0, stream>>>(We, be, q, Qe, cb, bcur, NB);
  hidden_ab<<<(N + BM - 1) / BM, 256, 0, stream>>>(x, W, b, q, hidden_h, Av, Bv, N);
  edge_aa_bin<<<bb, BIN_TPB, 0, stream>>>(el, ew, ef, Av, Bv, Qe, cb, bcur, recB,
                                          E, NB);
  gather_sorted<<<NB, 512, 0, stream>>>(bcur, recB, Av, Bv, hidden_h, outp, N);
}

// Round 13
// 355.958 us; speedup vs baseline: 1.0058x; 1.0058x over previous
//
#include <hip/hip_runtime.h>
#include <hip/hip_fp16.h>
#include <cstdint>
#include <cstddef>

#define SLOPE 0.2f
#define EPSV 1e-10f

#define BSHIFT 7                  // 128 nodes per sort bucket
#define BNODES (1 << BSHIFT)
#define NBMAX 1024                // bucket array bound for N <= 131072
#define BCAP 3584                 // fixed records/bucket region (mean 2048 + 34 sigma)
#define SEG_CAP 2816              // records per bucket LDS segment (mean + 17 sigma)
#define BIN_TPB 512
#define BIN_EPT 8                 // 4096 edges/block, 391 blocks — R7/R11 measured-best
#define BM 64

#define DOT4(F, Q) ((F).x*(Q).x + (F).y*(Q).y + (F).z*(Q).z + (F).w*(Q).w)

__device__ __forceinline__ float h2_as_float(__half2 v) {
  union { __half2 h; float f; } u; u.h = v; return u.f;
}
__device__ __forceinline__ __half2 float_as_h2(float v) {
  union { float f; __half2 h; } u; u.f = v; return u.h;
}
__device__ __forceinline__ __half2 u_as_h2(unsigned v) {
  union { unsigned u; __half2 h; } un; un.u = v; return un.h;
}
__device__ __forceinline__ unsigned h2_as_u(__half2 v) {
  union { __half2 h; unsigned u; } un; un.h = v; return un.u;
}

typedef float fv4 __attribute__((ext_vector_type(4)));
typedef int   iv2 __attribute__((ext_vector_type(2)));

__device__ __forceinline__ float4 ntload4(const float4* p) {
  fv4 v = __builtin_nontemporal_load((const fv4*)p);
  float4 r; r.x = v.x; r.y = v.y; r.z = v.z; r.w = v.w; return r;
}
__device__ __forceinline__ int2 ntload2i(const int2* p) {
  iv2 v = __builtin_nontemporal_load((const iv2*)p);
  int2 r; r.x = v.x; r.y = v.y; return r;
}
__device__ __forceinline__ float ntloadf(const float* p) {
  return __builtin_nontemporal_load(p);
}
__device__ __forceinline__ void ntstore4(float* p, float4 v) {
  fv4 t; t.x = v.x; t.y = v.y; t.z = v.z; t.w = v.w;
  __builtin_nontemporal_store(t, (fv4*)p);
}

// K1: hidden = x @ W^T + b (stored FP16), fused A[n,h], B[n,h] projections.
// Register-tiled SGEMM: 64 rows/block, 256 threads, 4x4 acc tile per thread,
// XOR-swizzled LDS operands (b128 reads at 2-way = free). [proven R6-R12]
// NEW (dispatch-count reduction, replaces prep_qe's bcur preset): each of the
// first nbkt blocks zeroes its bucket cursor — a single guarded store, no
// loops/atomics (NOT R8's fatal grid-stride fusion). Kernel-boundary ordering
// makes it visible to edge_aa_bin.
__global__ __launch_bounds__(256) void hidden_ab(
    const float* __restrict__ x, const float* __restrict__ W,
    const float* __restrict__ b, const float* __restrict__ query,
    __half* __restrict__ hidden_h, float* __restrict__ Av, float* __restrict__ Bv,
    unsigned* __restrict__ bcur, int nbkt, int N) {
  __shared__ float wt[128 * 64];   // wt[k*64 + (c ^ ((k&7)<<2))]
  __shared__ float xs[BM * 128];   // xs[r*128 + (k ^ ((r&7)<<2))]
  int t = threadIdx.x;
  int rowbase = blockIdx.x * BM;

  if (t == 0 && blockIdx.x < nbkt) bcur[blockIdx.x] = 0u;

#pragma unroll
  for (int i = 0; i < 32; ++i) {
    int idx = t + 256 * i;            // 0..8191 over flat W[c*128+k]
    int c = idx >> 7, k = idx & 127;
    wt[k * 64 + (c ^ ((k & 7) << 2))] = W[idx];
  }
#pragma unroll
  for (int i = 0; i < 8; ++i) {
    int idx4 = t + 256 * i;           // 0..2047 float4s (64 rows x 32)
    int r = idx4 >> 5, kc4 = idx4 & 31;
    int row = rowbase + r;
    float4 v = (row < N) ? ((const float4*)x)[(size_t)row * 32 + kc4]
                         : make_float4(0.f, 0.f, 0.f, 0.f);
    *(float4*)&xs[r * 128 + ((kc4 * 4) ^ ((r & 7) << 2))] = v;
  }
  __syncthreads();

  int tc = t & 15;            // col group: cols tc*4..tc*4+3
  int trg = t >> 4;           // row group: local rows trg*4..trg*4+3
  int c0 = tc * 4;
  const float* xb0 = &xs[(trg * 4 + 0) * 128];
  const float* xb1 = &xs[(trg * 4 + 1) * 128];
  const float* xb2 = &xs[(trg * 4 + 2) * 128];
  const float* xb3 = &xs[(trg * 4 + 3) * 128];
  const int sx0 = ((trg * 4 + 0) & 7) << 2;
  const int sx1 = ((trg * 4 + 1) & 7) << 2;
  const int sx2 = ((trg * 4 + 2) & 7) << 2;
  const int sx3 = ((trg * 4 + 3) & 7) << 2;

  float acc[4][4];
#pragma unroll
  for (int i = 0; i < 4; ++i)
#pragma unroll
    for (int j = 0; j < 4; ++j) acc[i][j] = 0.f;

#define ACCROW(i, XA) \
  acc[i][0] += (XA).x*wb0.x + (XA).y*wb1.x + (XA).z*wb2.x + (XA).w*wb3.x; \
  acc[i][1] += (XA).x*wb0.y + (XA).y*wb1.y + (XA).z*wb2.y + (XA).w*wb3.y; \
  acc[i][2] += (XA).x*wb0.z + (XA).y*wb1.z + (XA).z*wb2.z + (XA).w*wb3.z; \
  acc[i][3] += (XA).x*wb0.w + (XA).y*wb1.w + (XA).z*wb2.w + (XA).w*wb3.w;

#pragma unroll 2
  for (int k = 0; k < 128; k += 4) {
    float4 xa0 = *(const float4*)(xb0 + (k ^ sx0));
    float4 xa1 = *(const float4*)(xb1 + (k ^ sx1));
    float4 xa2 = *(const float4*)(xb2 + (k ^ sx2));
    float4 xa3 = *(const float4*)(xb3 + (k ^ sx3));
    float4 wb0 = *(const float4*)&wt[(k + 0) * 64 + (c0 ^ (((k + 0) & 7) << 2))];
    float4 wb1 = *(const float4*)&wt[(k + 1) * 64 + (c0 ^ (((k + 1) & 7) << 2))];
    float4 wb2 = *(const float4*)&wt[(k + 2) * 64 + (c0 ^ (((k + 2) & 7) << 2))];
    float4 wb3 = *(const float4*)&wt[(k + 3) * 64 + (c0 ^ (((k + 3) & 7) << 2))];
    ACCROW(0, xa0)
    ACCROW(1, xa1)
    ACCROW(2, xa2)
    ACCROW(3, xa3)
  }
#undef ACCROW

  float4 bv4 = ((const float4*)b)[tc];
  int h = tc >> 2;
  float qa[4], qb[4];
#pragma unroll
  for (int j = 0; j < 4; ++j) {
    int tt = (tc & 3) * 4 + j;
    qa[j] = query[h * 32 + 2 * tt];
    qb[j] = query[h * 32 + 2 * tt + 1];
  }
  float pa[4], pb[4];
#pragma unroll
  for (int i = 0; i < 4; ++i) {
    int row = rowbase + trg * 4 + i;
    float4 v;
    v.x = acc[i][0] + bv4.x; v.y = acc[i][1] + bv4.y;
    v.z = acc[i][2] + bv4.z; v.w = acc[i][3] + bv4.w;
    if (row < N) {
      uint2 hv;
      hv.x = h2_as_u(__floats2half2_rn(v.x, v.y));
      hv.y = h2_as_u(__floats2half2_rn(v.z, v.w));
      *(uint2*)(hidden_h + (size_t)row * 64 + c0) = hv;
    }
    pa[i] = qa[0]*v.x + qa[1]*v.y + qa[2]*v.z + qa[3]*v.w;
    pb[i] = qb[0]*v.x + qb[1]*v.y + qb[2]*v.z + qb[3]*v.w;
  }
#pragma unroll
  for (int mask = 1; mask <= 2; mask <<= 1) {
#pragma unroll
    for (int i = 0; i < 4; ++i) {
      pa[i] += __shfl_xor(pa[i], mask);
      pb[i] += __shfl_xor(pb[i], mask);
    }
  }
  if ((tc & 3) == 0) {
#pragma unroll
    for (int i = 0; i < 4; ++i) {
      int row = rowbase + trg * 4 + i;
      if (row < N) {
        Av[(size_t)row * 4 + h] = pa[i];
        Bv[(size_t)row * 4 + h] = pb[i];
      }
    }
  }
}

// K3: fused compute + bucket-bin, R11's proven shape (TPB=512, EPT=8, all
// loads+compute before the barrier, tight burst scatter at the end).
// NEW: prep_qe folded into the prologue — Qe[64]/cb[4] computed into LDS by
// the first 64 threads (wave-uniform broadcast reads in the main loop, no
// conflicts), covered by the existing first barrier. bcur now holds OFFSETS
// within each bucket (zeroed by hidden_ab); store position = bkt*BCAP + off.
__global__ __launch_bounds__(BIN_TPB) void edge_aa_bin(
    const int* __restrict__ el, const float* __restrict__ ew_arr,
    const float* __restrict__ ef,
    const float* __restrict__ Av, const float* __restrict__ Bv,
    const float* __restrict__ We, const float* __restrict__ be,
    const float* __restrict__ query,
    unsigned* __restrict__ bcur, float4* __restrict__ recB, int E, int nbkt) {
  __shared__ unsigned hist[NBMAX];
  __shared__ unsigned lbase[NBMAX];
  __shared__ float qe_s[64];
  __shared__ float cb_s[4];
  int t = threadIdx.x;
  int m0 = blockIdx.x * (BIN_TPB * BIN_EPT);
  if (t < 64) {
    int h = t >> 4, k = t & 15;
    float acc = 0.f;
    for (int tt = 0; tt < 16; ++tt) {
      float qs = query[h*32 + 2*tt] + query[h*32 + 2*tt + 1];
      acc += qs * We[(16*h + tt)*16 + k];
    }
    qe_s[h*16 + k] = acc;
    if (k == 0) {
      float accb = 0.f;
      for (int tt = 0; tt < 16; ++tt) {
        float qs = query[h*32 + 2*tt] + query[h*32 + 2*tt + 1];
        accb += qs * be[16*h + tt];
      }
      cb_s[h] = accb;
    }
  }
  for (int i = t; i < nbkt; i += BIN_TPB) hist[i] = 0u;
  __syncthreads();
  float4 r[BIN_EPT];
  int bkt[BIN_EPT];
  const float4* q4 = (const float4*)qe_s;
#pragma unroll
  for (int k = 0; k < BIN_EPT; ++k) {
    int m = m0 + t + BIN_TPB * k;
    bkt[k] = -1;
    if (m < E) {
      int2 e2 = ntload2i((const int2*)el + m);
      const float4* ef4 = (const float4*)(ef + (size_t)m * 16);
      float4 f0 = ntload4(ef4 + 0), f1 = ntload4(ef4 + 1);
      float4 f2 = ntload4(ef4 + 2), f3 = ntload4(ef4 + 3);
      float w0, w1, w2, w3;
      {
        float4 q;
        q = q4[0];  w0  = DOT4(f0, q);  q = q4[1];  w0 += DOT4(f1, q);
        q = q4[2];  w0 += DOT4(f2, q);  q = q4[3];  w0 += DOT4(f3, q);
        q = q4[4];  w1  = DOT4(f0, q);  q = q4[5];  w1 += DOT4(f1, q);
        q = q4[6];  w1 += DOT4(f2, q);  q = q4[7];  w1 += DOT4(f3, q);
        q = q4[8];  w2  = DOT4(f0, q);  q = q4[9];  w2 += DOT4(f1, q);
        q = q4[10]; w2 += DOT4(f2, q);  q = q4[11]; w2 += DOT4(f3, q);
        q = q4[12]; w3  = DOT4(f0, q);  q = q4[13]; w3 += DOT4(f1, q);
        q = q4[14]; w3 += DOT4(f2, q);  q = q4[15]; w3 += DOT4(f3, q);
      }
      float4 av = ((const float4*)Av)[e2.x];
      float4 bv = ((const float4*)Bv)[e2.y];
      w0 += av.x + bv.x + cb_s[0];
      w1 += av.y + bv.y + cb_s[1];
      w2 += av.z + bv.z + cb_s[2];
      w3 += av.w + bv.w + cb_s[3];
      w0 = w0 > 0.f ? w0 : SLOPE * w0;
      w1 = w1 > 0.f ? w1 : SLOPE * w1;
      w2 = w2 > 0.f ? w2 : SLOPE * w2;
      w3 = w3 > 0.f ? w3 : SLOPE * w3;
      float ew = ntloadf(ew_arr + m);
      float a0 = __expf(w0) * ew, a1 = __expf(w1) * ew;
      float a2 = __expf(w2) * ew, a3 = __expf(w3) * ew;
      r[k].x = __int_as_float(e2.x);
      r[k].y = h2_as_float(__floats2half2_rn(a0, a1));
      r[k].z = h2_as_float(__floats2half2_rn(a2, a3));
      r[k].w = __int_as_float(e2.y);
      bkt[k] = e2.y >> BSHIFT;
      atomicAdd(&hist[bkt[k]], 1u);
    }
  }
  __syncthreads();
  for (int i = t; i < nbkt; i += BIN_TPB) {
    unsigned c = hist[i];
    lbase[i] = c ? atomicAdd(&bcur[i], c) : 0u;   // offset within bucket
  }
  __syncthreads();
  for (int i = t; i < nbkt; i += BIN_TPB) hist[i] = 0u;
  __syncthreads();
#pragma unroll
  for (int k = 0; k < BIN_EPT; ++k) {
    if (bkt[k] >= 0) {
      unsigned off = lbase[bkt[k]] + atomicAdd(&hist[bkt[k]], 1u);
      if (off < BCAP)                              // overflow guard (34-sigma)
        recB[(size_t)bkt[k] * BCAP + off] = r[k];
    }
  }
}

// K4: fused CSR-build + gather. One block per 128-node bucket: in-block
// histogram of nout&127 over the bucket span (len = bcur[b], offset
// semantics), 128-wide Hillis-Steele scan, L2-hot re-read scattering into
// the 12B/record LDS segment, then the proven 4-group x 16-lane gather with
// 2-way unrolled hidden loads (2x MLP). Block-uniform fallback for
// len > SEG_CAP (~never): full-span scan per node.
__global__ __launch_bounds__(512) void gather_sorted(
    const unsigned* __restrict__ bcur, const float4* __restrict__ recB,
    const float* __restrict__ Av, const float* __restrict__ Bv,
    const __half* __restrict__ hidden_h, float* __restrict__ out, int N) {
  __shared__ unsigned seg_nin[SEG_CAP];
  __shared__ uint2    seg_aa[SEG_CAP];
  __shared__ unsigned cnt[BNODES];      // counts -> inclusive scan
  __shared__ unsigned rp2[BNODES + 1];  // exclusive offsets
  __shared__ unsigned cur[BNODES];
  int t = threadIdx.x;
  int b = blockIdx.x;
  int n0 = b << BSHIFT;
  int nCnt = N - n0; if (nCnt > BNODES) nCnt = BNODES;
  unsigned base = (unsigned)b * BCAP;
  unsigned len = bcur[b];
  if (len > BCAP) len = BCAP;
  if (t < BNODES) cnt[t] = 0u;
  __syncthreads();

  // pass 1: per-node histogram over the bucket span
  for (unsigned i = t; i < len; i += 512) {
    float4 r = recB[base + i];
    int nloc = __float_as_int(r.w) & (BNODES - 1);
    atomicAdd(&cnt[nloc], 1u);
  }
  __syncthreads();
  // inclusive Hillis-Steele scan over cnt[0..127] (block-uniform barriers)
  for (int off = 1; off < BNODES; off <<= 1) {
    unsigned v = (t < BNODES && t >= off) ? cnt[t - off] : 0u;
    __syncthreads();
    if (t < BNODES) cnt[t] += v;
    __syncthreads();
  }
  if (t < BNODES) rp2[t + 1] = cnt[t];
  if (t == 0) rp2[0] = 0u;
  __syncthreads();
  if (t < BNODES) cur[t] = rp2[t];
  __syncthreads();

  bool fits = (len <= SEG_CAP);
  if (fits) {
    // pass 2: L2-hot re-read, scatter into LDS segment at exact CSR offsets
    for (unsigned i = t; i < len; i += 512) {
      float4 r = recB[base + i];
      int nloc = __float_as_int(r.w) & (BNODES - 1);
      unsigned p = atomicAdd(&cur[nloc], 1u);
      seg_nin[p] = (unsigned)__float_as_int(r.x);
      seg_aa[p] = make_uint2(__float_as_uint(r.y), __float_as_uint(r.z));
    }
  }
  __syncthreads();

  int w = t >> 6, lane = t & 63;
  int g = lane >> 4, j = lane & 15, h = j >> 2;
  for (int loc = w; loc < nCnt; loc += 8) {
    int n = n0 + loc;
    unsigned i0 = rp2[loc], i1 = rp2[loc + 1];
    float4 acc = make_float4(0.f, 0.f, 0.f, 0.f);
    float nsum = 0.f;

    if (g == 0) {
      float4 av = ((const float4*)Av)[n];
      float4 bv = ((const float4*)Bv)[n];
      float avh = (h == 0) ? av.x : (h == 1) ? av.y : (h == 2) ? av.z : av.w;
      float bvh = (h == 0) ? bv.x : (h == 1) ? bv.y : (h == 2) ? bv.z : bv.w;
      float wsl = avh + bvh;
      wsl = wsl > 0.f ? wsl : SLOPE * wsl;
      float aas = __expf(wsl);
      nsum = aas;
      uint2 hv = *(const uint2*)(hidden_h + (size_t)n * 64 + 4 * j);
      float2 f01 = __half22float2(u_as_h2(hv.x));
      float2 f23 = __half22float2(u_as_h2(hv.y));
      acc.x = aas * f01.x; acc.y = aas * f01.y;
      acc.z = aas * f23.x; acc.w = aas * f23.y;
    }

    if (fits) {
      for (unsigned idx = i0 + g; idx < i1; idx += 8) {
        unsigned nin1 = seg_nin[idx];
        uint2 aa1 = seg_aa[idx];
        uint2 hv1 = *(const uint2*)(hidden_h + (size_t)nin1 * 64 + 4 * j);
        unsigned idx2 = idx + 4;
        bool have2 = (idx2 < i1);
        unsigned nin2 = 0; uint2 aa2 = make_uint2(0u, 0u);
        uint2 hv2 = make_uint2(0u, 0u);
        if (have2) {
          nin2 = seg_nin[idx2];
          aa2 = seg_aa[idx2];
          hv2 = *(const uint2*)(hidden_h + (size_t)nin2 * 64 + 4 * j);
        }
        {
          __half2 aa01 = u_as_h2(aa1.x), aa23 = u_as_h2(aa1.y);
          float aa = (h == 0) ? __low2float(aa01) : (h == 1) ? __high2float(aa01)
                   : (h == 2) ? __low2float(aa23) : __high2float(aa23);
          float2 f01 = __half22float2(u_as_h2(hv1.x));
          float2 f23 = __half22float2(u_as_h2(hv1.y));
          nsum += aa;
          acc.x += aa * f01.x; acc.y += aa * f01.y;
          acc.z += aa * f23.x; acc.w += aa * f23.y;
        }
        if (have2) {
          __half2 aa01 = u_as_h2(aa2.x), aa23 = u_as_h2(aa2.y);
          float aa = (h == 0) ? __low2float(aa01) : (h == 1) ? __high2float(aa01)
                   : (h == 2) ? __low2float(aa23) : __high2float(aa23);
          float2 f01 = __half22float2(u_as_h2(hv2.x));
          float2 f23 = __half22float2(u_as_h2(hv2.y));
          nsum += aa;
          acc.x += aa * f01.x; acc.y += aa * f01.y;
          acc.z += aa * f23.x; acc.w += aa * f23.y;
        }
      }
    } else {
      for (unsigned i = g; i < len; i += 4) {
        float4 rr = recB[base + i];
        int nloc = __float_as_int(rr.w) & (BNODES - 1);
        if (nloc != loc) continue;
        int nin = __float_as_int(rr.x);
        __half2 aa01 = float_as_h2(rr.y);
        __half2 aa23 = float_as_h2(rr.z);
        float aa = (h == 0) ? __low2float(aa01) : (h == 1) ? __high2float(aa01)
                 : (h == 2) ? __low2float(aa23) : __high2float(aa23);
        uint2 hv = *(const uint2*)(hidden_h + (size_t)nin * 64 + 4 * j);
        float2 f01 = __half22float2(u_as_h2(hv.x));
        float2 f23 = __half22float2(u_as_h2(hv.y));
        nsum += aa;
        acc.x += aa * f01.x; acc.y += aa * f01.y;
        acc.z += aa * f23.x; acc.w += aa * f23.y;
      }
    }

#pragma unroll
    for (int mask = 16; mask <= 32; mask <<= 1) {
      acc.x += __shfl_xor(acc.x, mask);
      acc.y += __shfl_xor(acc.y, mask);
      acc.z += __shfl_xor(acc.z, mask);
      acc.w += __shfl_xor(acc.w, mask);
      nsum  += __shfl_xor(nsum, mask);
    }
    if (g == 0) {
      float c = (float)(i1 - i0 + 1u);
      float F = 1.f / ((nsum / c + EPSV) * c);
      float4 v;
      v.x = acc.x * F; v.y = acc.y * F; v.z = acc.z * F; v.w = acc.w * F;
      v.x = v.x > 0.f ? v.x : 0.f;
      v.y = v.y > 0.f ? v.y : 0.f;
      v.z = v.z > 0.f ? v.z : 0.f;
      v.w = v.w > 0.f ? v.w : 0.f;
      ntstore4(out + (size_t)n * 64 + 4 * j, v);
    }
  }
}

extern "C" void kernel_launch(void* const* d_in, const int* in_sizes, int n_in,
                              void* d_out, int out_size, void* d_ws, size_t ws_size,
                              hipStream_t stream) {
  const int*   el = (const int*)d_in[0];
  const float* ew = (const float*)d_in[1];
  const float* ef = (const float*)d_in[2];
  const float* x  = (const float*)d_in[4];
  const float* W  = (const float*)d_in[5];
  const float* b  = (const float*)d_in[6];
  const float* We = (const float*)d_in[7];
  const float* be = (const float*)d_in[8];
  const float* q  = (const float*)d_in[9];
  int E = in_sizes[0] / 2;
  int N = in_sizes[4] / 128;
  int NB = (N + BNODES - 1) >> BSHIFT;     // 782 for N=100k

  float* ws = (float*)d_ws;
  size_t off = 0;
  __half* hidden_h = (__half*)(ws + off); off += (size_t)N * 32;   // N*64 halves
  float4* recB  = (float4*)(ws + off); off += (size_t)NB * BCAP * 4 + 16;
  float* Av     = ws + off; off += (size_t)N * 4;
  float* Bv     = ws + off; off += (size_t)N * 4;
  unsigned* bcur = (unsigned*)(ws + off); off += NBMAX;
  float* outp   = (float*)d_out;

  int bb = (E + BIN_TPB * BIN_EPT - 1) / (BIN_TPB * BIN_EPT);     // 391

  hidden_ab<<<(N + BM - 1) / BM, 256, 0, stream>>>(x, W, b, q, hidden_h, Av, Bv,
                                                   bcur, NB, N);
  edge_aa_bin<<<bb, BIN_TPB, 0, stream>>>(el, ew, ef, Av, Bv, We, be, q,
                                          bcur, recB, E, NB);
  gather_sorted<<<NB, 512, 0, stream>>>(bcur, recB, Av, Bv, hidden_h, outp, N);
}

// Round 14
// 345.229 us; speedup vs baseline: 1.0370x; 1.0311x over previous
//
#include <hip/hip_runtime.h>
#include <hip/hip_fp16.h>
#include <cstdint>
#include <cstddef>

#define SLOPE 0.2f
#define EPSV 1e-10f

#define BSHIFT 7                  // 128 nodes per sort bucket
#define BNODES (1 << BSHIFT)
#define NBMAX 1024                // bucket array bound for N <= 131072
#define BCAP 3584                 // fixed records/bucket region (mean 2048 + 34 sigma)
#define SEG_CAP 2816              // records per bucket LDS segment (mean + 17 sigma)
#define BIN_TPB 512
#define BIN_EPT 8                 // 4096 edges/block, 391 blocks — R7/R11 measured-best
#define BM 64

#define DOT4(F, Q) ((F).x*(Q).x + (F).y*(Q).y + (F).z*(Q).z + (F).w*(Q).w)

__device__ __forceinline__ float h2_as_float(__half2 v) {
  union { __half2 h; float f; } u; u.h = v; return u.f;
}
__device__ __forceinline__ __half2 float_as_h2(float v) {
  union { float f; __half2 h; } u; u.f = v; return u.h;
}
__device__ __forceinline__ __half2 u_as_h2(unsigned v) {
  union { unsigned u; __half2 h; } un; un.u = v; return un.h;
}
__device__ __forceinline__ unsigned h2_as_u(__half2 v) {
  union { __half2 h; unsigned u; } un; un.h = v; return un.u;
}

typedef float fv4 __attribute__((ext_vector_type(4)));
typedef int   iv2 __attribute__((ext_vector_type(2)));

__device__ __forceinline__ float4 ntload4(const float4* p) {
  fv4 v = __builtin_nontemporal_load((const fv4*)p);
  float4 r; r.x = v.x; r.y = v.y; r.z = v.z; r.w = v.w; return r;
}
__device__ __forceinline__ int2 ntload2i(const int2* p) {
  iv2 v = __builtin_nontemporal_load((const iv2*)p);
  int2 r; r.x = v.x; r.y = v.y; return r;
}
__device__ __forceinline__ float ntloadf(const float* p) {
  return __builtin_nontemporal_load(p);
}
__device__ __forceinline__ void ntstore4(float* p, float4 v) {
  fv4 t; t.x = v.x; t.y = v.y; t.z = v.z; t.w = v.w;
  __builtin_nontemporal_store(t, (fv4*)p);
}

// K1: hidden = x @ W^T + b (stored FP16), fused A[n,h], B[n,h] projections.
// Register-tiled SGEMM: 64 rows/block, 256 threads, 4x4 acc tile per thread,
// XOR-swizzled LDS operands. Also zeroes bcur (single guarded store/block).
__global__ __launch_bounds__(256) void hidden_ab(
    const float* __restrict__ x, const float* __restrict__ W,
    const float* __restrict__ b, const float* __restrict__ query,
    __half* __restrict__ hidden_h, float* __restrict__ Av, float* __restrict__ Bv,
    unsigned* __restrict__ bcur, int nbkt, int N) {
  __shared__ float wt[128 * 64];   // wt[k*64 + (c ^ ((k&7)<<2))]
  __shared__ float xs[BM * 128];   // xs[r*128 + (k ^ ((r&7)<<2))]
  int t = threadIdx.x;
  int rowbase = blockIdx.x * BM;

  if (t == 0 && blockIdx.x < nbkt) bcur[blockIdx.x] = 0u;

#pragma unroll
  for (int i = 0; i < 32; ++i) {
    int idx = t + 256 * i;            // 0..8191 over flat W[c*128+k]
    int c = idx >> 7, k = idx & 127;
    wt[k * 64 + (c ^ ((k & 7) << 2))] = W[idx];
  }
#pragma unroll
  for (int i = 0; i < 8; ++i) {
    int idx4 = t + 256 * i;           // 0..2047 float4s (64 rows x 32)
    int r = idx4 >> 5, kc4 = idx4 & 31;
    int row = rowbase + r;
    float4 v = (row < N) ? ((const float4*)x)[(size_t)row * 32 + kc4]
                         : make_float4(0.f, 0.f, 0.f, 0.f);
    *(float4*)&xs[r * 128 + ((kc4 * 4) ^ ((r & 7) << 2))] = v;
  }
  __syncthreads();

  int tc = t & 15;            // col group: cols tc*4..tc*4+3
  int trg = t >> 4;           // row group: local rows trg*4..trg*4+3
  int c0 = tc * 4;
  const float* xb0 = &xs[(trg * 4 + 0) * 128];
  const float* xb1 = &xs[(trg * 4 + 1) * 128];
  const float* xb2 = &xs[(trg * 4 + 2) * 128];
  const float* xb3 = &xs[(trg * 4 + 3) * 128];
  const int sx0 = ((trg * 4 + 0) & 7) << 2;
  const int sx1 = ((trg * 4 + 1) & 7) << 2;
  const int sx2 = ((trg * 4 + 2) & 7) << 2;
  const int sx3 = ((trg * 4 + 3) & 7) << 2;

  float acc[4][4];
#pragma unroll
  for (int i = 0; i < 4; ++i)
#pragma unroll
    for (int j = 0; j < 4; ++j) acc[i][j] = 0.f;

#define ACCROW(i, XA) \
  acc[i][0] += (XA).x*wb0.x + (XA).y*wb1.x + (XA).z*wb2.x + (XA).w*wb3.x; \
  acc[i][1] += (XA).x*wb0.y + (XA).y*wb1.y + (XA).z*wb2.y + (XA).w*wb3.y; \
  acc[i][2] += (XA).x*wb0.z + (XA).y*wb1.z + (XA).z*wb2.z + (XA).w*wb3.z; \
  acc[i][3] += (XA).x*wb0.w + (XA).y*wb1.w + (XA).z*wb2.w + (XA).w*wb3.w;

#pragma unroll 2
  for (int k = 0; k < 128; k += 4) {
    float4 xa0 = *(const float4*)(xb0 + (k ^ sx0));
    float4 xa1 = *(const float4*)(xb1 + (k ^ sx1));
    float4 xa2 = *(const float4*)(xb2 + (k ^ sx2));
    float4 xa3 = *(const float4*)(xb3 + (k ^ sx3));
    float4 wb0 = *(const float4*)&wt[(k + 0) * 64 + (c0 ^ (((k + 0) & 7) << 2))];
    float4 wb1 = *(const float4*)&wt[(k + 1) * 64 + (c0 ^ (((k + 1) & 7) << 2))];
    float4 wb2 = *(const float4*)&wt[(k + 2) * 64 + (c0 ^ (((k + 2) & 7) << 2))];
    float4 wb3 = *(const float4*)&wt[(k + 3) * 64 + (c0 ^ (((k + 3) & 7) << 2))];
    ACCROW(0, xa0)
    ACCROW(1, xa1)
    ACCROW(2, xa2)
    ACCROW(3, xa3)
  }
#undef ACCROW

  float4 bv4 = ((const float4*)b)[tc];
  int h = tc >> 2;
  float qa[4], qb[4];
#pragma unroll
  for (int j = 0; j < 4; ++j) {
    int tt = (tc & 3) * 4 + j;
    qa[j] = query[h * 32 + 2 * tt];
    qb[j] = query[h * 32 + 2 * tt + 1];
  }
  float pa[4], pb[4];
#pragma unroll
  for (int i = 0; i < 4; ++i) {
    int row = rowbase + trg * 4 + i;
    float4 v;
    v.x = acc[i][0] + bv4.x; v.y = acc[i][1] + bv4.y;
    v.z = acc[i][2] + bv4.z; v.w = acc[i][3] + bv4.w;
    if (row < N) {
      uint2 hv;
      hv.x = h2_as_u(__floats2half2_rn(v.x, v.y));
      hv.y = h2_as_u(__floats2half2_rn(v.z, v.w));
      *(uint2*)(hidden_h + (size_t)row * 64 + c0) = hv;
    }
    pa[i] = qa[0]*v.x + qa[1]*v.y + qa[2]*v.z + qa[3]*v.w;
    pb[i] = qb[0]*v.x + qb[1]*v.y + qb[2]*v.z + qb[3]*v.w;
  }
#pragma unroll
  for (int mask = 1; mask <= 2; mask <<= 1) {
#pragma unroll
    for (int i = 0; i < 4; ++i) {
      pa[i] += __shfl_xor(pa[i], mask);
      pb[i] += __shfl_xor(pb[i], mask);
    }
  }
  if ((tc & 3) == 0) {
#pragma unroll
    for (int i = 0; i < 4; ++i) {
      int row = rowbase + trg * 4 + i;
      if (row < N) {
        Av[(size_t)row * 4 + h] = pa[i];
        Bv[(size_t)row * 4 + h] = pb[i];
      }
    }
  }
}

// K3: fused compute + bucket-bin (R11 shape: loads+compute before barrier,
// tight burst scatter at end). R14 change: PAIR-SPLIT ef loads — lanes
// 2k/2k+1 each load 32B (2 float4) of edge k, consecutive lanes 32B apart
// (2 lanes/line -> 128 line-requests per 64 edges vs 256 for the old
// per-lane 64B pattern); half-dots combined via 8 cheap shfl_xor(.,1); a
// second load pair covers edges 32..63 and lane l owns edge
// chunk + 32*(l&1) + (l>>1) downstream — full parallelism, no predication,
// 8-deep MLP and register budget unchanged. Tests the divergent-request-
// throughput theory (occupancy 12..31% all gave ~80-83us; VALU 8%, HBM 19%).
__global__ __launch_bounds__(BIN_TPB) void edge_aa_bin(
    const int* __restrict__ el, const float* __restrict__ ew_arr,
    const float* __restrict__ ef,
    const float* __restrict__ Av, const float* __restrict__ Bv,
    const float* __restrict__ We, const float* __restrict__ be,
    const float* __restrict__ query,
    unsigned* __restrict__ bcur, float4* __restrict__ recB, int E, int nbkt) {
  __shared__ unsigned hist[NBMAX];
  __shared__ unsigned lbase[NBMAX];
  __shared__ float qe_s[64];
  __shared__ float cb_s[4];
  int t = threadIdx.x;
  int m0 = blockIdx.x * (BIN_TPB * BIN_EPT);
  if (t < 64) {
    int h = t >> 4, k = t & 15;
    float acc = 0.f;
    for (int tt = 0; tt < 16; ++tt) {
      float qs = query[h*32 + 2*tt] + query[h*32 + 2*tt + 1];
      acc += qs * We[(16*h + tt)*16 + k];
    }
    qe_s[h*16 + k] = acc;
    if (k == 0) {
      float accb = 0.f;
      for (int tt = 0; tt < 16; ++tt) {
        float qs = query[h*32 + 2*tt] + query[h*32 + 2*tt + 1];
        accb += qs * be[16*h + tt];
      }
      cb_s[h] = accb;
    }
  }
  for (int i = t; i < nbkt; i += BIN_TPB) hist[i] = 0u;
  __syncthreads();

  int lane = t & 63, wv = t >> 6;
  int p = lane & 1;               // which half of the edge this lane loads
  const float4* ef4f = (const float4*)ef;
  const float4* q4 = (const float4*)qe_s;

  float4 r[BIN_EPT];
  int bkt[BIN_EPT];
#pragma unroll
  for (int k = 0; k < BIN_EPT; ++k) {
    int chunk = m0 + BIN_TPB * k + (wv << 6);   // first edge of this wave's 64
    int ea = chunk + (lane >> 1);               // pair's edge in group A
    int eb = ea + 32;                           // pair's edge in group B
    float4 fa0 = make_float4(0.f,0.f,0.f,0.f), fa1 = fa0, fb0 = fa0, fb1 = fa0;
    if (ea < E) {
      fa0 = ntload4(ef4f + (size_t)ea * 4 + 2 * p);
      fa1 = ntload4(ef4f + (size_t)ea * 4 + 2 * p + 1);
    }
    if (eb < E) {
      fb0 = ntload4(ef4f + (size_t)eb * 4 + 2 * p);
      fb1 = ntload4(ef4f + (size_t)eb * 4 + 2 * p + 1);
    }
    // half-dots: this lane's 2 quarters (2p, 2p+1) against Qe
    float pa0, pa1, pa2, pa3, pb0, pb1, pb2, pb3;
    {
      float4 qA0 = q4[0*4 + 2*p], qA1 = q4[0*4 + 2*p + 1];
      float4 qB0 = q4[1*4 + 2*p], qB1 = q4[1*4 + 2*p + 1];
      float4 qC0 = q4[2*4 + 2*p], qC1 = q4[2*4 + 2*p + 1];
      float4 qD0 = q4[3*4 + 2*p], qD1 = q4[3*4 + 2*p + 1];
      pa0 = DOT4(fa0, qA0) + DOT4(fa1, qA1);
      pa1 = DOT4(fa0, qB0) + DOT4(fa1, qB1);
      pa2 = DOT4(fa0, qC0) + DOT4(fa1, qC1);
      pa3 = DOT4(fa0, qD0) + DOT4(fa1, qD1);
      pb0 = DOT4(fb0, qA0) + DOT4(fb1, qA1);
      pb1 = DOT4(fb0, qB0) + DOT4(fb1, qB1);
      pb2 = DOT4(fb0, qC0) + DOT4(fb1, qC1);
      pb3 = DOT4(fb0, qD0) + DOT4(fb1, qD1);
    }
    // combine pair halves (xor-1 DPP, both lanes get the full dot)
    pa0 += __shfl_xor(pa0, 1); pa1 += __shfl_xor(pa1, 1);
    pa2 += __shfl_xor(pa2, 1); pa3 += __shfl_xor(pa3, 1);
    pb0 += __shfl_xor(pb0, 1); pb1 += __shfl_xor(pb1, 1);
    pb2 += __shfl_xor(pb2, 1); pb3 += __shfl_xor(pb3, 1);
    // lane takes ownership of one edge: p=0 -> ea (group A), p=1 -> eb' where
    // eb' uses this lane's own (lane>>1): m = chunk + 32p + (lane>>1)
    int m = chunk + 32 * p + (lane >> 1);
    float w0 = p ? pb0 : pa0;
    float w1 = p ? pb1 : pa1;
    float w2 = p ? pb2 : pa2;
    float w3 = p ? pb3 : pa3;
    bkt[k] = -1;
    if (m < E) {
      int2 e2 = ntload2i((const int2*)el + m);
      float4 av = ((const float4*)Av)[e2.x];
      float4 bv = ((const float4*)Bv)[e2.y];
      w0 += av.x + bv.x + cb_s[0];
      w1 += av.y + bv.y + cb_s[1];
      w2 += av.z + bv.z + cb_s[2];
      w3 += av.w + bv.w + cb_s[3];
      w0 = w0 > 0.f ? w0 : SLOPE * w0;
      w1 = w1 > 0.f ? w1 : SLOPE * w1;
      w2 = w2 > 0.f ? w2 : SLOPE * w2;
      w3 = w3 > 0.f ? w3 : SLOPE * w3;
      float ew = ntloadf(ew_arr + m);
      float a0 = __expf(w0) * ew, a1 = __expf(w1) * ew;
      float a2 = __expf(w2) * ew, a3 = __expf(w3) * ew;
      r[k].x = __int_as_float(e2.x);
      r[k].y = h2_as_float(__floats2half2_rn(a0, a1));
      r[k].z = h2_as_float(__floats2half2_rn(a2, a3));
      r[k].w = __int_as_float(e2.y);
      bkt[k] = e2.y >> BSHIFT;
      atomicAdd(&hist[bkt[k]], 1u);
    }
  }
  __syncthreads();
  for (int i = t; i < nbkt; i += BIN_TPB) {
    unsigned c = hist[i];
    lbase[i] = c ? atomicAdd(&bcur[i], c) : 0u;   // offset within bucket
  }
  __syncthreads();
  for (int i = t; i < nbkt; i += BIN_TPB) hist[i] = 0u;
  __syncthreads();
#pragma unroll
  for (int k = 0; k < BIN_EPT; ++k) {
    if (bkt[k] >= 0) {
      unsigned off = lbase[bkt[k]] + atomicAdd(&hist[bkt[k]], 1u);
      if (off < BCAP)                              // overflow guard (34-sigma)
        recB[(size_t)bkt[k] * BCAP + off] = r[k];
    }
  }
}

// K4: fused CSR-build + gather. One block per 128-node bucket: in-block
// histogram of nout&127 over the bucket span (len = bcur[b]), 128-wide
// Hillis-Steele scan, L2-hot re-read scattering into the 12B/record LDS
// segment, then the proven 4-group x 16-lane gather with 2-way unrolled
// hidden loads (2x MLP). Block-uniform fallback for len > SEG_CAP (~never).
__global__ __launch_bounds__(512) void gather_sorted(
    const unsigned* __restrict__ bcur, const float4* __restrict__ recB,
    const float* __restrict__ Av, const float* __restrict__ Bv,
    const __half* __restrict__ hidden_h, float* __restrict__ out, int N) {
  __shared__ unsigned seg_nin[SEG_CAP];
  __shared__ uint2    seg_aa[SEG_CAP];
  __shared__ unsigned cnt[BNODES];      // counts -> inclusive scan
  __shared__ unsigned rp2[BNODES + 1];  // exclusive offsets
  __shared__ unsigned cur[BNODES];
  int t = threadIdx.x;
  int b = blockIdx.x;
  int n0 = b << BSHIFT;
  int nCnt = N - n0; if (nCnt > BNODES) nCnt = BNODES;
  unsigned base = (unsigned)b * BCAP;
  unsigned len = bcur[b];
  if (len > BCAP) len = BCAP;
  if (t < BNODES) cnt[t] = 0u;
  __syncthreads();

  for (unsigned i = t; i < len; i += 512) {
    float4 r = recB[base + i];
    int nloc = __float_as_int(r.w) & (BNODES - 1);
    atomicAdd(&cnt[nloc], 1u);
  }
  __syncthreads();
  for (int off = 1; off < BNODES; off <<= 1) {
    unsigned v = (t < BNODES && t >= off) ? cnt[t - off] : 0u;
    __syncthreads();
    if (t < BNODES) cnt[t] += v;
    __syncthreads();
  }
  if (t < BNODES) rp2[t + 1] = cnt[t];
  if (t == 0) rp2[0] = 0u;
  __syncthreads();
  if (t < BNODES) cur[t] = rp2[t];
  __syncthreads();

  bool fits = (len <= SEG_CAP);
  if (fits) {
    for (unsigned i = t; i < len; i += 512) {
      float4 r = recB[base + i];
      int nloc = __float_as_int(r.w) & (BNODES - 1);
      unsigned p = atomicAdd(&cur[nloc], 1u);
      seg_nin[p] = (unsigned)__float_as_int(r.x);
      seg_aa[p] = make_uint2(__float_as_uint(r.y), __float_as_uint(r.z));
    }
  }
  __syncthreads();

  int w = t >> 6, lane = t & 63;
  int g = lane >> 4, j = lane & 15, h = j >> 2;
  for (int loc = w; loc < nCnt; loc += 8) {
    int n = n0 + loc;
    unsigned i0 = rp2[loc], i1 = rp2[loc + 1];
    float4 acc = make_float4(0.f, 0.f, 0.f, 0.f);
    float nsum = 0.f;

    if (g == 0) {
      float4 av = ((const float4*)Av)[n];
      float4 bv = ((const float4*)Bv)[n];
      float avh = (h == 0) ? av.x : (h == 1) ? av.y : (h == 2) ? av.z : av.w;
      float bvh = (h == 0) ? bv.x : (h == 1) ? bv.y : (h == 2) ? bv.z : bv.w;
      float wsl = avh + bvh;
      wsl = wsl > 0.f ? wsl : SLOPE * wsl;
      float aas = __expf(wsl);
      nsum = aas;
      uint2 hv = *(const uint2*)(hidden_h + (size_t)n * 64 + 4 * j);
      float2 f01 = __half22float2(u_as_h2(hv.x));
      float2 f23 = __half22float2(u_as_h2(hv.y));
      acc.x = aas * f01.x; acc.y = aas * f01.y;
      acc.z = aas * f23.x; acc.w = aas * f23.y;
    }

    if (fits) {
      for (unsigned idx = i0 + g; idx < i1; idx += 8) {
        unsigned nin1 = seg_nin[idx];
        uint2 aa1 = seg_aa[idx];
        uint2 hv1 = *(const uint2*)(hidden_h + (size_t)nin1 * 64 + 4 * j);
        unsigned idx2 = idx + 4;
        bool have2 = (idx2 < i1);
        unsigned nin2 = 0; uint2 aa2 = make_uint2(0u, 0u);
        uint2 hv2 = make_uint2(0u, 0u);
        if (have2) {
          nin2 = seg_nin[idx2];
          aa2 = seg_aa[idx2];
          hv2 = *(const uint2*)(hidden_h + (size_t)nin2 * 64 + 4 * j);
        }
        {
          __half2 aa01 = u_as_h2(aa1.x), aa23 = u_as_h2(aa1.y);
          float aa = (h == 0) ? __low2float(aa01) : (h == 1) ? __high2float(aa01)
                   : (h == 2) ? __low2float(aa23) : __high2float(aa23);
          float2 f01 = __half22float2(u_as_h2(hv1.x));
          float2 f23 = __half22float2(u_as_h2(hv1.y));
          nsum += aa;
          acc.x += aa * f01.x; acc.y += aa * f01.y;
          acc.z += aa * f23.x; acc.w += aa * f23.y;
        }
        if (have2) {
          __half2 aa01 = u_as_h2(aa2.x), aa23 = u_as_h2(aa2.y);
          float aa = (h == 0) ? __low2float(aa01) : (h == 1) ? __high2float(aa01)
                   : (h == 2) ? __low2float(aa23) : __high2float(aa23);
          float2 f01 = __half22float2(u_as_h2(hv2.x));
          float2 f23 = __half22float2(u_as_h2(hv2.y));
          nsum += aa;
          acc.x += aa * f01.x; acc.y += aa * f01.y;
          acc.z += aa * f23.x; acc.w += aa * f23.y;
        }
      }
    } else {
      for (unsigned i = g; i < len; i += 4) {
        float4 rr = recB[base + i];
        int nloc = __float_as_int(rr.w) & (BNODES - 1);
        if (nloc != loc) continue;
        int nin = __float_as_int(rr.x);
        __half2 aa01 = float_as_h2(rr.y);
        __half2 aa23 = float_as_h2(rr.z);
        float aa = (h == 0) ? __low2float(aa01) : (h == 1) ? __high2float(aa01)
                 : (h == 2) ? __low2float(aa23) : __high2float(aa23);
        uint2 hv = *(const uint2*)(hidden_h + (size_t)nin * 64 + 4 * j);
        float2 f01 = __half22float2(u_as_h2(hv.x));
        float2 f23 = __half22float2(u_as_h2(hv.y));
        nsum += aa;
        acc.x += aa * f01.x; acc.y += aa * f01.y;
        acc.z += aa * f23.x; acc.w += aa * f23.y;
      }
    }

#pragma unroll
    for (int mask = 16; mask <= 32; mask <<= 1) {
      acc.x += __shfl_xor(acc.x, mask);
      acc.y += __shfl_xor(acc.y, mask);
      acc.z += __shfl_xor(acc.z, mask);
      acc.w += __shfl_xor(acc.w, mask);
      nsum  += __shfl_xor(nsum, mask);
    }
    if (g == 0) {
      float c = (float)(i1 - i0 + 1u);
      float F = 1.f / ((nsum / c + EPSV) * c);
      float4 v;
      v.x = acc.x * F; v.y = acc.y * F; v.z = acc.z * F; v.w = acc.w * F;
      v.x = v.x > 0.f ? v.x : 0.f;
      v.y = v.y > 0.f ? v.y : 0.f;
      v.z = v.z > 0.f ? v.z : 0.f;
      v.w = v.w > 0.f ? v.w : 0.f;
      ntstore4(out + (size_t)n * 64 + 4 * j, v);
    }
  }
}

extern "C" void kernel_launch(void* const* d_in, const int* in_sizes, int n_in,
                              void* d_out, int out_size, void* d_ws, size_t ws_size,
                              hipStream_t stream) {
  const int*   el = (const int*)d_in[0];
  const float* ew = (const float*)d_in[1];
  const float* ef = (const float*)d_in[2];
  const float* x  = (const float*)d_in[4];
  const float* W  = (const float*)d_in[5];
  const float* b  = (const float*)d_in[6];
  const float* We = (const float*)d_in[7];
  const float* be = (const float*)d_in[8];
  const float* q  = (const float*)d_in[9];
  int E = in_sizes[0] / 2;
  int N = in_sizes[4] / 128;
  int NB = (N + BNODES - 1) >> BSHIFT;     // 782 for N=100k

  float* ws = (float*)d_ws;
  size_t off = 0;
  __half* hidden_h = (__half*)(ws + off); off += (size_t)N * 32;   // N*64 halves
  float4* recB  = (float4*)(ws + off); off += (size_t)NB * BCAP * 4 + 16;
  float* Av     = ws + off; off += (size_t)N * 4;
  float* Bv     = ws + off; off += (size_t)N * 4;
  unsigned* bcur = (unsigned*)(ws + off); off += NBMAX;
  float* outp   = (float*)d_out;

  int bb = (E + BIN_TPB * BIN_EPT - 1) / (BIN_TPB * BIN_EPT);     // 391

  hidden_ab<<<(N + BM - 1) / BM, 256, 0, stream>>>(x, W, b, q, hidden_h, Av, Bv,
                                                   bcur, NB, N);
  edge_aa_bin<<<bb, BIN_TPB, 0, stream>>>(el, ew, ef, Av, Bv, We, be, q,
                                          bcur, recB, E, NB);
  gather_sorted<<<NB, 512, 0, stream>>>(bcur, recB, Av, Bv, hidden_h, outp, N);
}